// Round 2
// baseline (232.318 us; speedup 1.0000x reference)
//
#include <hip/hip_runtime.h>
#include <cstdint>
#include <cstddef>

#define EMB  1024
#define DM   64
#define NH   16
#define SLEN 2048
#define BS   2

typedef _Float16 f16x8 __attribute__((ext_vector_type(8)));
typedef _Float16 f16x4 __attribute__((ext_vector_type(4)));
typedef __fp16   hf2   __attribute__((ext_vector_type(2)));
typedef __fp16   hf4   __attribute__((ext_vector_type(4)));
typedef __fp16   hf8   __attribute__((ext_vector_type(8)));
typedef float    f32x4 __attribute__((ext_vector_type(4)));

#define ASYNC_LD16(gp, lp)                                                        \
    __builtin_amdgcn_global_load_lds(                                             \
        (const __attribute__((address_space(1))) void*)(gp),                      \
        (__attribute__((address_space(3))) void*)(lp), 16, 0, 0)

// ---------------------------------------------------------------------------
// prep: z<3 -> fp32->fp16 flat convert of Q/K/V; z>=3 -> weight transpose
// convert W[K][N] fp32 -> W^T[N][K] fp16 (z-3 selects among 4 weights).
// ---------------------------------------------------------------------------
__global__ __launch_bounds__(256)
void prep(const float* __restrict__ Q, const float* __restrict__ K,
          const float* __restrict__ V,
          const float* __restrict__ Wq, const float* __restrict__ Wk,
          const float* __restrict__ Wv, const float* __restrict__ Wo,
          _Float16* __restrict__ Qh, _Float16* __restrict__ Kh,
          _Float16* __restrict__ Vh,
          _Float16* __restrict__ WqT, _Float16* __restrict__ WkT,
          _Float16* __restrict__ WvT, _Float16* __restrict__ WoT)
{
    __shared__ float t[64][65];
    const int z = blockIdx.z;
    if (z < 3) {
        const float* in  = (z == 0) ? Q : (z == 1) ? K : V;
        _Float16*    out = (z == 0) ? Qh : (z == 1) ? Kh : Vh;
        size_t i = ((size_t)blockIdx.x * 256 + threadIdx.x) * 8;
        float4 a = *(const float4*)(in + i);
        float4 b = *(const float4*)(in + i + 4);
        f16x8 o;
        o[0] = (_Float16)a.x; o[1] = (_Float16)a.y; o[2] = (_Float16)a.z; o[3] = (_Float16)a.w;
        o[4] = (_Float16)b.x; o[5] = (_Float16)b.y; o[6] = (_Float16)b.z; o[7] = (_Float16)b.w;
        *(f16x8*)(out + i) = o;
        return;
    }
    if (blockIdx.x >= 256) return;
    const float* W;
    _Float16*    T;
    switch (z - 3) {
        case 0:  W = Wq; T = WqT; break;
        case 1:  W = Wk; T = WkT; break;
        case 2:  W = Wv; T = WvT; break;
        default: W = Wo; T = WoT; break;
    }
    const int tid = threadIdx.x;
    const int bn  = (blockIdx.x & 15) * 64;
    const int bk  = (blockIdx.x >> 4) * 64;

    #pragma unroll
    for (int p = 0; p < 4; ++p) {
        int row = p * 16 + (tid >> 4);
        int col = (tid & 15) * 4;
        float4 v = *(const float4*)(W + (size_t)(bk + row) * EMB + bn + col);
        t[row][col+0] = v.x; t[row][col+1] = v.y; t[row][col+2] = v.z; t[row][col+3] = v.w;
    }
    __syncthreads();
    #pragma unroll
    for (int p = 0; p < 4; ++p) {
        int nr = p * 16 + (tid >> 4);
        int kc = (tid & 15) * 4;
        f16x4 o;
        o[0] = (_Float16)t[kc+0][nr];
        o[1] = (_Float16)t[kc+1][nr];
        o[2] = (_Float16)t[kc+2][nr];
        o[3] = (_Float16)t[kc+3][nr];
        *(f16x4*)&T[(size_t)(bn + nr) * EMB + bk + kc] = o;
    }
}

// ---------------------------------------------------------------------------
// MFMA GEMM core (m97 structure): C = scale*(A @ Bt^T + bias)
// ---------------------------------------------------------------------------
__device__ __forceinline__
void gemm_core(const _Float16* __restrict__ A, const _Float16* __restrict__ Bt,
               const float* __restrict__ bias, float* __restrict__ Cf,
               _Float16* __restrict__ Ch, int M, int N, int K,
               float scale, int mode, int bx, int by)
{
    __shared__ __align__(16) _Float16 As[128 * 32];
    __shared__ __align__(16) _Float16 Bs[128 * 32];

    const int tid  = threadIdx.x;
    const int lane = tid & 63;
    const int wave = tid >> 6;
    const int c    = lane & 15;
    const int quad = lane >> 4;
    const int bm   = by * 128;
    const int bn   = bx * 128;
    const int wm   = (wave >> 1) * 64;
    const int wn   = (wave & 1) * 64;

    f32x4 acc[4][4];
    #pragma unroll
    for (int i = 0; i < 4; ++i)
        #pragma unroll
        for (int j = 0; j < 4; ++j)
            #pragma unroll
            for (int r = 0; r < 4; ++r) acc[i][j][r] = 0.f;

    const char* gA = (const char*)(A + (size_t)(bm + (tid >> 2)) * K) + (tid & 3) * 16;
    const char* gB = (const char*)(Bt + (size_t)(bn + (tid >> 2)) * K) + (tid & 3) * 16;
    char* lA = (char*)As + wave * 1024;
    char* lB = (char*)Bs + wave * 1024;
    const size_t rowskip = (size_t)64 * K * 2;

    for (int k0 = 0; k0 < K; k0 += 32) {
        __syncthreads();
        ASYNC_LD16(gA + (size_t)k0 * 2,           lA);
        ASYNC_LD16(gA + rowskip + (size_t)k0 * 2, lA + 4096);
        ASYNC_LD16(gB + (size_t)k0 * 2,           lB);
        ASYNC_LD16(gB + rowskip + (size_t)k0 * 2, lB + 4096);
        __syncthreads();

        f16x8 af[4], bf[4];
        #pragma unroll
        for (int i = 0; i < 4; ++i)
            af[i] = *(const f16x8*)&As[(wm + i * 16 + c) * 32 + quad * 8];
        #pragma unroll
        for (int j = 0; j < 4; ++j)
            bf[j] = *(const f16x8*)&Bs[(wn + j * 16 + c) * 32 + quad * 8];

        #pragma unroll
        for (int i = 0; i < 4; ++i)
            #pragma unroll
            for (int j = 0; j < 4; ++j)
                acc[i][j] = __builtin_amdgcn_mfma_f32_16x16x32_f16(af[i], bf[j], acc[i][j], 0, 0, 0);
    }

    float bcol[4];
    #pragma unroll
    for (int j = 0; j < 4; ++j) bcol[j] = bias[bn + wn + j * 16 + c];

    #pragma unroll
    for (int i = 0; i < 4; ++i) {
        int m0 = bm + wm + i * 16 + quad * 4;
        #pragma unroll
        for (int j = 0; j < 4; ++j) {
            int n = bn + wn + j * 16 + c;
            if (mode == 0) {
                #pragma unroll
                for (int r = 0; r < 4; ++r)
                    Cf[(size_t)(m0 + r) * N + n] = acc[i][j][r] + bcol[j];
            } else if (mode == 1) {
                int h = n >> 6, d = n & 63;
                #pragma unroll
                for (int r = 0; r < 4; ++r) {
                    int mm = m0 + r;
                    int b = mm >> 11, l = mm & (SLEN - 1);
                    Ch[(((size_t)(b * NH + h)) * SLEN + l) * DM + d] =
                        (_Float16)((acc[i][j][r] + bcol[j]) * scale);
                }
            } else {
                int h = n >> 6, d = n & 63;
                int b = m0 >> 11, l = m0 & (SLEN - 1);
                f16x4 o;
                #pragma unroll
                for (int r = 0; r < 4; ++r)
                    o[r] = (_Float16)(acc[i][j][r] + bcol[j]);
                *(f16x4*)&Ch[(((size_t)(b * NH + h)) * DM + d) * SLEN + l] = o;
            }
        }
    }
}

__global__ __launch_bounds__(256)
void gemm_qkv(const _Float16* __restrict__ Qh, const _Float16* __restrict__ Kh,
              const _Float16* __restrict__ Vh,
              const _Float16* __restrict__ WqT, const _Float16* __restrict__ WkT,
              const _Float16* __restrict__ WvT,
              const float* __restrict__ bq, const float* __restrict__ bk,
              const float* __restrict__ bv,
              _Float16* __restrict__ q_ws, _Float16* __restrict__ k_ws,
              _Float16* __restrict__ v_ws)
{
    const _Float16 *A, *Bt;
    const float* bias;
    _Float16* Ch;
    float scale;
    int mode;
    // q-scale folds 1/sqrt(DM) AND log2(e) so attention can use exp2 directly.
    if (blockIdx.z == 0)      { A = Qh; Bt = WqT; bias = bq; Ch = q_ws; scale = 0.18033688f; mode = 1; }
    else if (blockIdx.z == 1) { A = Kh; Bt = WkT; bias = bk; Ch = k_ws; scale = 1.0f;        mode = 1; }
    else                      { A = Vh; Bt = WvT; bias = bv; Ch = v_ws; scale = 1.0f;        mode = 2; }
    gemm_core(A, Bt, bias, nullptr, Ch, BS * SLEN, NH * DM, EMB, scale, mode,
              blockIdx.x, blockIdx.y);
}

__global__ __launch_bounds__(256)
void gemm_out(const _Float16* __restrict__ Oh, const _Float16* __restrict__ WoT,
              const float* __restrict__ bo, float* __restrict__ out)
{
    gemm_core(Oh, WoT, bo, out, nullptr, BS * SLEN, EMB, NH * DM, 1.0f, 0,
              blockIdx.x, blockIdx.y);
}

// ---------------------------------------------------------------------------
// MFMA flash attention v7: v6 structure (all-K=32 MFMA, S^T trick, no-max
// exp2 softmax, XOR-swizzled LDS, global_load_lds staging) but reorganized
// from 4 waves x 32 q-rows to 8 waves x 16 q-rows (512-thread blocks).
// Same grid (512 blocks) -> 16 waves/CU instead of 8: 4 waves/SIMD to hide
// ds_read (~120cy) + exp-chain latency that capped v6 at 2 waves/SIMD
// (MfmaUtil 26 / VALUBusy 38 / HBM 17% -- nothing saturated).
// qw/kw: [b][h][l][d] fp16;  vwT: [b][h][d][l] fp16;  ow: [b][l][h*64+d] fp16
// ---------------------------------------------------------------------------
__global__ __launch_bounds__(512)
void attn_mfma(const _Float16* __restrict__ qw, const _Float16* __restrict__ kw,
               const _Float16* __restrict__ vwT, _Float16* __restrict__ ow)
{
    // swizzled: element (row, col) at row*64 + ((col/8 ^ (row&7))*8 + col%8)
    __shared__ __align__(16) _Float16 Kt[2][64 * 64];   // [key][d]
    __shared__ __align__(16) _Float16 Vt[2][64 * 64];   // [d][key]

    const int tid  = threadIdx.x;
    const int lane = tid & 63;
    const int wave = tid >> 6;          // 0..7
    const int c    = lane & 15;
    const int quad = lane >> 4;
    const int bh   = blockIdx.y;
    const int b    = bh >> 4;
    const int h    = bh & 15;
    const int qbase = blockIdx.x * 128 + wave * 16;   // 16 q-rows per wave

    const _Float16* kb = kw  + (size_t)bh * SLEN * DM;
    const _Float16* vb = vwT + (size_t)bh * DM * SLEN;
    const _Float16* qb = qw  + (size_t)bh * SLEN * DM;

    // Q fragments (B-operand of S^T = K Q^T): lane: qrow = c, d = ch*32+quad*8+j
    f16x8 qf[2];
    #pragma unroll
    for (int ch = 0; ch < 2; ++ch)
        qf[ch] = *(const f16x8*)(qb + (size_t)(qbase + c) * DM + ch*32 + quad*8);

    f32x4 oacc[4];
    f32x4 lacc;
    #pragma unroll
    for (int dg = 0; dg < 4; ++dg)
        #pragma unroll
        for (int r = 0; r < 4; ++r) oacc[dg][r] = 0.f;
    #pragma unroll
    for (int r = 0; r < 4; ++r) lacc[r] = 0.f;

    const f16x8 ones8 = {(_Float16)1.f, (_Float16)1.f, (_Float16)1.f, (_Float16)1.f,
                         (_Float16)1.f, (_Float16)1.f, (_Float16)1.f, (_Float16)1.f};
    const f32x4 zero4 = {0.f, 0.f, 0.f, 0.f};

    // --- global_load_lds staging: wave w stages LDS bytes [w*1024, w*1024+1024)
    // of each 8 KB buffer; lane's 16 B goes to dest o = w*1024 + lane*16
    // -> row = o/128 = w*8 + lane/8, phys chunk = lane&7.  Source supplies the
    // swizzled chunk: logical chunk = (lane&7) ^ (row&7), row&7 = (lane>>3)&7.
    const int r0  = wave * 8 + (lane >> 3);
    const int lc0 = (((lane & 7) ^ ((lane >> 3) & 7)) * 16);
    const char* gk = (const char*)kb + r0 * 128 + lc0;             // K row stride 128 B
    const char* gv = (const char*)vb + (size_t)r0 * 4096 + lc0;    // V^T row stride 4096 B
    char* lK = (char*)&Kt[0][0] + wave * 1024;
    char* lV = (char*)&Vt[0][0] + wave * 1024;

    // preload tile 0 into buffer 0
    ASYNC_LD16(gk, lK);
    ASYNC_LD16(gv, lV);
    gk += 8192; gv += 128;
    __syncthreads();

    auto tile = [&](int cur) {
        // prefetch next tile into the other buffer (over-reads past the last
        // tile stay inside the workspace -- values unused)
        {
            char* pk = (char*)&Kt[cur ^ 1][0] + wave * 1024;
            char* pv = (char*)&Vt[cur ^ 1][0] + wave * 1024;
            ASYNC_LD16(gk, pk);
            ASYNC_LD16(gv, pv);
            gk += 8192; gv += 128;
        }

        // K fragments (A-operand): key = g*16+c, logical chunk ch*4+quad
        f16x8 kf[4][2];
        #pragma unroll
        for (int g = 0; g < 4; ++g)
            #pragma unroll
            for (int ch = 0; ch < 2; ++ch)
                kf[g][ch] = *(const f16x8*)
                    &Kt[cur][(g*16 + c) * 64 + (((ch*4 + quad) ^ (c & 7)) * 8)];

        // S^T = K Q^T : lane: key = g*16+quad*4+r, qrow = c
        f32x4 s[4];
        #pragma unroll
        for (int g = 0; g < 4; ++g) {
            s[g] = __builtin_amdgcn_mfma_f32_16x16x32_f16(kf[g][0], qf[0], zero4, 0, 0, 0);
            s[g] = __builtin_amdgcn_mfma_f32_16x16x32_f16(kf[g][1], qf[1], s[g],  0, 0, 0);
        }

        // p = 2^(s') via raw v_exp_f32 + packed f16 converts, packed directly
        // into the K=32 A-fragment order: pf8[kk] element j holds
        // key = kk*32 + (j>=4)*16 + quad*4 + (j&3)  (j<4 from g=2kk, j>=4 from g=2kk+1)
        f16x8 pf8[2];
        #pragma unroll
        for (int kk = 0; kk < 2; ++kk) {
            hf4 h4[2];
            #pragma unroll
            for (int u = 0; u < 2; ++u) {
                float p0 = __builtin_amdgcn_exp2f(s[2*kk + u][0]);
                float p1 = __builtin_amdgcn_exp2f(s[2*kk + u][1]);
                float p2 = __builtin_amdgcn_exp2f(s[2*kk + u][2]);
                float p3 = __builtin_amdgcn_exp2f(s[2*kk + u][3]);
                hf2 lo = __builtin_amdgcn_cvt_pkrtz(p0, p1);
                hf2 hi = __builtin_amdgcn_cvt_pkrtz(p2, p3);
                h4[u] = __builtin_shufflevector(lo, hi, 0, 1, 2, 3);
            }
            hf8 h8 = __builtin_shufflevector(h4[0], h4[1], 0, 1, 2, 3, 4, 5, 6, 7);
            pf8[kk] = __builtin_bit_cast(f16x8, h8);
        }

        // l += P @ ones  (K=32; with B = ones any k-permutation is valid)
        #pragma unroll
        for (int kk = 0; kk < 2; ++kk)
            lacc = __builtin_amdgcn_mfma_f32_16x16x32_f16(pf8[kk], ones8, lacc, 0, 0, 0);

        // O += P V  (K=32: B element j = V[key(quad,j)][d=dg*16+c], i.e. the
        // same four f16x4 LDS reads as before, concatenated in pairs)
        #pragma unroll
        for (int dg = 0; dg < 4; ++dg) {
            f16x4 vf[4];
            #pragma unroll
            for (int g = 0; g < 4; ++g)
                vf[g] = *(const f16x4*)
                    &Vt[cur][(dg*16 + c) * 64 +
                             (((2*g + (quad >> 1)) ^ (c & 7)) * 8) + (quad & 1) * 4];
            f16x8 v01 = __builtin_shufflevector(vf[0], vf[1], 0, 1, 2, 3, 4, 5, 6, 7);
            f16x8 v23 = __builtin_shufflevector(vf[2], vf[3], 0, 1, 2, 3, 4, 5, 6, 7);
            oacc[dg] = __builtin_amdgcn_mfma_f32_16x16x32_f16(pf8[0], v01, oacc[dg], 0, 0, 0);
            oacc[dg] = __builtin_amdgcn_mfma_f32_16x16x32_f16(pf8[1], v23, oacc[dg], 0, 0, 0);
        }
        __syncthreads();
    };

    for (int it = 0; it < SLEN / 64; it += 2) {
        tile(0);
        tile(1);
    }

    // epilogue: lacc rows (quad*4+r) align with oacc rows -- no shuffles
    #pragma unroll
    for (int r = 0; r < 4; ++r) {
        float linv = 1.0f / lacc[r];
        int row = qbase + quad*4 + r;
        #pragma unroll
        for (int dg = 0; dg < 4; ++dg)
            ow[((size_t)b * SLEN + row) * EMB + h * DM + dg*16 + c] =
                (_Float16)(oacc[dg][r] * linv);
    }
}

// ---------------------------------------------------------------------------
extern "C" void kernel_launch(void* const* d_in, const int* in_sizes, int n_in,
                              void* d_out, int out_size, void* d_ws, size_t ws_size,
                              hipStream_t stream)
{
    const float* Q  = (const float*)d_in[0];
    const float* K  = (const float*)d_in[1];
    const float* V  = (const float*)d_in[2];
    const float* Wq = (const float*)d_in[3];
    const float* bq = (const float*)d_in[4];
    const float* Wk = (const float*)d_in[5];
    const float* bk = (const float*)d_in[6];
    const float* Wv = (const float*)d_in[7];
    const float* bv = (const float*)d_in[8];
    const float* Wo = (const float*)d_in[9];
    const float* bo = (const float*)d_in[10];
    float* out = (float*)d_out;

    const size_t MN = (size_t)BS * SLEN * NH * DM;   // 4M halves
    const size_t WW = (size_t)EMB * NH * DM;         // 1M halves

    _Float16* base = (_Float16*)d_ws;
    _Float16* Qh   = base;
    _Float16* Kh   = Qh  + MN;
    _Float16* Vh   = Kh  + MN;
    _Float16* WqT  = Vh  + MN;
    _Float16* WkT  = WqT + WW;
    _Float16* WvT  = WkT + WW;
    _Float16* WoT  = WvT + WW;
    _Float16* q_ws = WoT + WW;
    _Float16* k_ws = q_ws + MN;
    _Float16* v_ws = k_ws + MN;
    _Float16* o_ws = v_ws + MN;

    dim3 blk(256);

    prep<<<dim3(2048, 1, 7), blk, 0, stream>>>(Q, K, V, Wq, Wk, Wv, Wo,
                                               Qh, Kh, Vh, WqT, WkT, WvT, WoT);

    gemm_qkv<<<dim3(8, 32, 3), blk, 0, stream>>>(Qh, Kh, Vh, WqT, WkT, WvT,
                                                 bq, bk, bv, q_ws, k_ws, v_ws);

    attn_mfma<<<dim3(SLEN / 128, BS * NH), dim3(512), 0, stream>>>(q_ws, k_ws, v_ws, o_ws);

    gemm_out<<<dim3(8, 32, 1), blk, 0, stream>>>(o_ws, WoT, bo, out);
}

// Round 3
// 224.821 us; speedup vs baseline: 1.0333x; 1.0333x over previous
//
#include <hip/hip_runtime.h>
#include <cstdint>
#include <cstddef>

#define EMB  1024
#define DM   64
#define NH   16
#define SLEN 2048
#define BS   2

typedef _Float16 f16x8 __attribute__((ext_vector_type(8)));
typedef _Float16 f16x4 __attribute__((ext_vector_type(4)));
typedef __fp16   hf2   __attribute__((ext_vector_type(2)));
typedef __fp16   hf4   __attribute__((ext_vector_type(4)));
typedef __fp16   hf8   __attribute__((ext_vector_type(8)));
typedef float    f32x4 __attribute__((ext_vector_type(4)));

#define ASYNC_LD16(gp, lp)                                                        \
    __builtin_amdgcn_global_load_lds(                                             \
        (const __attribute__((address_space(1))) void*)(gp),                      \
        (__attribute__((address_space(3))) void*)(lp), 16, 0, 0)

// ---------------------------------------------------------------------------
// prep: z<3 -> fp32->fp16 flat convert of Q/K/V; z>=3 -> weight transpose
// convert W[K][N] fp32 -> W^T[N][K] fp16 (z-3 selects among 4 weights).
// ---------------------------------------------------------------------------
__global__ __launch_bounds__(256)
void prep(const float* __restrict__ Q, const float* __restrict__ K,
          const float* __restrict__ V,
          const float* __restrict__ Wq, const float* __restrict__ Wk,
          const float* __restrict__ Wv, const float* __restrict__ Wo,
          _Float16* __restrict__ Qh, _Float16* __restrict__ Kh,
          _Float16* __restrict__ Vh,
          _Float16* __restrict__ WqT, _Float16* __restrict__ WkT,
          _Float16* __restrict__ WvT, _Float16* __restrict__ WoT)
{
    __shared__ float t[64][65];
    const int z = blockIdx.z;
    if (z < 3) {
        const float* in  = (z == 0) ? Q : (z == 1) ? K : V;
        _Float16*    out = (z == 0) ? Qh : (z == 1) ? Kh : Vh;
        size_t i = ((size_t)blockIdx.x * 256 + threadIdx.x) * 8;
        float4 a = *(const float4*)(in + i);
        float4 b = *(const float4*)(in + i + 4);
        f16x8 o;
        o[0] = (_Float16)a.x; o[1] = (_Float16)a.y; o[2] = (_Float16)a.z; o[3] = (_Float16)a.w;
        o[4] = (_Float16)b.x; o[5] = (_Float16)b.y; o[6] = (_Float16)b.z; o[7] = (_Float16)b.w;
        *(f16x8*)(out + i) = o;
        return;
    }
    if (blockIdx.x >= 256) return;
    const float* W;
    _Float16*    T;
    switch (z - 3) {
        case 0:  W = Wq; T = WqT; break;
        case 1:  W = Wk; T = WkT; break;
        case 2:  W = Wv; T = WvT; break;
        default: W = Wo; T = WoT; break;
    }
    const int tid = threadIdx.x;
    const int bn  = (blockIdx.x & 15) * 64;
    const int bk  = (blockIdx.x >> 4) * 64;

    #pragma unroll
    for (int p = 0; p < 4; ++p) {
        int row = p * 16 + (tid >> 4);
        int col = (tid & 15) * 4;
        float4 v = *(const float4*)(W + (size_t)(bk + row) * EMB + bn + col);
        t[row][col+0] = v.x; t[row][col+1] = v.y; t[row][col+2] = v.z; t[row][col+3] = v.w;
    }
    __syncthreads();
    #pragma unroll
    for (int p = 0; p < 4; ++p) {
        int nr = p * 16 + (tid >> 4);
        int kc = (tid & 15) * 4;
        f16x4 o;
        o[0] = (_Float16)t[kc+0][nr];
        o[1] = (_Float16)t[kc+1][nr];
        o[2] = (_Float16)t[kc+2][nr];
        o[3] = (_Float16)t[kc+3][nr];
        *(f16x4*)&T[(size_t)(bn + nr) * EMB + bk + kc] = o;
    }
}

// ---------------------------------------------------------------------------
// MFMA GEMM core (m97 structure): C = scale*(A @ Bt^T + bias)
// ---------------------------------------------------------------------------
__device__ __forceinline__
void gemm_core(const _Float16* __restrict__ A, const _Float16* __restrict__ Bt,
               const float* __restrict__ bias, float* __restrict__ Cf,
               _Float16* __restrict__ Ch, int M, int N, int K,
               float scale, int mode, int bx, int by)
{
    __shared__ __align__(16) _Float16 As[128 * 32];
    __shared__ __align__(16) _Float16 Bs[128 * 32];

    const int tid  = threadIdx.x;
    const int lane = tid & 63;
    const int wave = tid >> 6;
    const int c    = lane & 15;
    const int quad = lane >> 4;
    const int bm   = by * 128;
    const int bn   = bx * 128;
    const int wm   = (wave >> 1) * 64;
    const int wn   = (wave & 1) * 64;

    f32x4 acc[4][4];
    #pragma unroll
    for (int i = 0; i < 4; ++i)
        #pragma unroll
        for (int j = 0; j < 4; ++j)
            #pragma unroll
            for (int r = 0; r < 4; ++r) acc[i][j][r] = 0.f;

    const char* gA = (const char*)(A + (size_t)(bm + (tid >> 2)) * K) + (tid & 3) * 16;
    const char* gB = (const char*)(Bt + (size_t)(bn + (tid >> 2)) * K) + (tid & 3) * 16;
    char* lA = (char*)As + wave * 1024;
    char* lB = (char*)Bs + wave * 1024;
    const size_t rowskip = (size_t)64 * K * 2;

    for (int k0 = 0; k0 < K; k0 += 32) {
        __syncthreads();
        ASYNC_LD16(gA + (size_t)k0 * 2,           lA);
        ASYNC_LD16(gA + rowskip + (size_t)k0 * 2, lA + 4096);
        ASYNC_LD16(gB + (size_t)k0 * 2,           lB);
        ASYNC_LD16(gB + rowskip + (size_t)k0 * 2, lB + 4096);
        __syncthreads();

        f16x8 af[4], bf[4];
        #pragma unroll
        for (int i = 0; i < 4; ++i)
            af[i] = *(const f16x8*)&As[(wm + i * 16 + c) * 32 + quad * 8];
        #pragma unroll
        for (int j = 0; j < 4; ++j)
            bf[j] = *(const f16x8*)&Bs[(wn + j * 16 + c) * 32 + quad * 8];

        #pragma unroll
        for (int i = 0; i < 4; ++i)
            #pragma unroll
            for (int j = 0; j < 4; ++j)
                acc[i][j] = __builtin_amdgcn_mfma_f32_16x16x32_f16(af[i], bf[j], acc[i][j], 0, 0, 0);
    }

    float bcol[4];
    #pragma unroll
    for (int j = 0; j < 4; ++j) bcol[j] = bias[bn + wn + j * 16 + c];

    #pragma unroll
    for (int i = 0; i < 4; ++i) {
        int m0 = bm + wm + i * 16 + quad * 4;
        #pragma unroll
        for (int j = 0; j < 4; ++j) {
            int n = bn + wn + j * 16 + c;
            if (mode == 0) {
                #pragma unroll
                for (int r = 0; r < 4; ++r)
                    Cf[(size_t)(m0 + r) * N + n] = acc[i][j][r] + bcol[j];
            } else if (mode == 1) {
                int h = n >> 6, d = n & 63;
                #pragma unroll
                for (int r = 0; r < 4; ++r) {
                    int mm = m0 + r;
                    int b = mm >> 11, l = mm & (SLEN - 1);
                    Ch[(((size_t)(b * NH + h)) * SLEN + l) * DM + d] =
                        (_Float16)((acc[i][j][r] + bcol[j]) * scale);
                }
            } else {
                int h = n >> 6, d = n & 63;
                int b = m0 >> 11, l = m0 & (SLEN - 1);
                f16x4 o;
                #pragma unroll
                for (int r = 0; r < 4; ++r)
                    o[r] = (_Float16)(acc[i][j][r] + bcol[j]);
                *(f16x4*)&Ch[(((size_t)(b * NH + h)) * DM + d) * SLEN + l] = o;
            }
        }
    }
}

__global__ __launch_bounds__(256)
void gemm_qkv(const _Float16* __restrict__ Qh, const _Float16* __restrict__ Kh,
              const _Float16* __restrict__ Vh,
              const _Float16* __restrict__ WqT, const _Float16* __restrict__ WkT,
              const _Float16* __restrict__ WvT,
              const float* __restrict__ bq, const float* __restrict__ bk,
              const float* __restrict__ bv,
              _Float16* __restrict__ q_ws, _Float16* __restrict__ k_ws,
              _Float16* __restrict__ v_ws)
{
    const _Float16 *A, *Bt;
    const float* bias;
    _Float16* Ch;
    float scale;
    int mode;
    // q-scale folds 1/sqrt(DM) AND log2(e) so attention can use exp2 directly.
    if (blockIdx.z == 0)      { A = Qh; Bt = WqT; bias = bq; Ch = q_ws; scale = 0.18033688f; mode = 1; }
    else if (blockIdx.z == 1) { A = Kh; Bt = WkT; bias = bk; Ch = k_ws; scale = 1.0f;        mode = 1; }
    else                      { A = Vh; Bt = WvT; bias = bv; Ch = v_ws; scale = 1.0f;        mode = 2; }
    gemm_core(A, Bt, bias, nullptr, Ch, BS * SLEN, NH * DM, EMB, scale, mode,
              blockIdx.x, blockIdx.y);
}

__global__ __launch_bounds__(256)
void gemm_out(const _Float16* __restrict__ Oh, const _Float16* __restrict__ WoT,
              const float* __restrict__ bo, float* __restrict__ out)
{
    gemm_core(Oh, WoT, bo, out, nullptr, BS * SLEN, EMB, NH * DM, 1.0f, 0,
              blockIdx.x, blockIdx.y);
}

// ---------------------------------------------------------------------------
// MFMA flash attention v8: v7 was LDS-issue-bound (~94% of CU cycles:
// 8 waves x (8 ds_read_b128 + 16 ds_read_b64) per tile + 8.4M conflict
// cycles).  v8 splits the 8 waves as 4 q-groups (32 rows) x 2 key-halves
// (32 keys): each wave reads only its key-half's K/V fragments -> per-wave
// LDS issue halves (4 b128 + 8 b64), same all-K=32 MFMA count.  Partial
// (O, l) over key-halves are merged once at the end through LDS (two
// barrier-separated 20 KB rounds; last-tile prefetch skipped so no stray
// global_load_lds writes race the merge).
// qw/kw: [b][h][l][d] fp16;  vwT: [b][h][d][l] fp16;  ow: [b][l][h*64+d] fp16
// ---------------------------------------------------------------------------
__global__ __launch_bounds__(512)
void attn_mfma(const _Float16* __restrict__ qw, const _Float16* __restrict__ kw,
               const _Float16* __restrict__ vwT, _Float16* __restrict__ ow)
{
    // swizzled: element (row, col) at row*64 + ((col/8 ^ (row&7))*8 + col%8)
    __shared__ __align__(16) _Float16 Kt[2][64 * 64];   // [key][d]
    __shared__ __align__(16) _Float16 Vt[2][64 * 64];   // [d][key]

    const int tid  = threadIdx.x;
    const int lane = tid & 63;
    const int wave = tid >> 6;          // 0..7
    const int c    = lane & 15;
    const int quad = lane >> 4;
    const int qg   = wave & 3;          // q-group: 32 rows
    const int kh   = wave >> 2;         // key-half: 32 keys
    const int bh   = blockIdx.y;
    const int b    = bh >> 4;
    const int h    = bh & 15;
    const int qbase = blockIdx.x * 128 + qg * 32;

    const _Float16* kb = kw  + (size_t)bh * SLEN * DM;
    const _Float16* vb = vwT + (size_t)bh * DM * SLEN;
    const _Float16* qb = qw  + (size_t)bh * SLEN * DM;

    // Q fragments (B-operand of S^T = K Q^T): lane: qrow = t*16+c, d = ch*32+quad*8+j
    f16x8 qf[2][2];
    #pragma unroll
    for (int t = 0; t < 2; ++t)
        #pragma unroll
        for (int ch = 0; ch < 2; ++ch)
            qf[t][ch] = *(const f16x8*)(qb + (size_t)(qbase + t*16 + c) * DM + ch*32 + quad*8);

    f32x4 oacc[2][4];
    f32x4 lacc[2];
    #pragma unroll
    for (int t = 0; t < 2; ++t) {
        #pragma unroll
        for (int dg = 0; dg < 4; ++dg)
            #pragma unroll
            for (int r = 0; r < 4; ++r) oacc[t][dg][r] = 0.f;
        #pragma unroll
        for (int r = 0; r < 4; ++r) lacc[t][r] = 0.f;
    }

    const f16x8 ones8 = {(_Float16)1.f, (_Float16)1.f, (_Float16)1.f, (_Float16)1.f,
                         (_Float16)1.f, (_Float16)1.f, (_Float16)1.f, (_Float16)1.f};
    const f32x4 zero4 = {0.f, 0.f, 0.f, 0.f};

    // --- global_load_lds staging: wave w stages LDS bytes [w*1024, w*1024+1024)
    // of each 8 KB buffer; lane's 16 B goes to dest o = w*1024 + lane*16
    // -> row = w*8 + lane/8, phys chunk = lane&7.  Source supplies the
    // swizzled chunk: logical chunk = (lane&7) ^ (row&7), row&7 = (lane>>3)&7.
    const int r0  = wave * 8 + (lane >> 3);
    const int lc0 = (((lane & 7) ^ ((lane >> 3) & 7)) * 16);
    const char* gk = (const char*)kb + r0 * 128 + lc0;             // K row stride 128 B
    const char* gv = (const char*)vb + (size_t)r0 * 4096 + lc0;    // V^T row stride 4096 B
    char* lK = (char*)&Kt[0][0] + wave * 1024;
    char* lV = (char*)&Vt[0][0] + wave * 1024;

    // preload tile 0 into buffer 0
    ASYNC_LD16(gk, lK);
    ASYNC_LD16(gv, lV);
    gk += 8192; gv += 128;
    __syncthreads();

    auto tile = [&](int cur, bool pf) {
        // prefetch next tile into the other buffer
        if (pf) {
            char* pk = (char*)&Kt[cur ^ 1][0] + wave * 1024;
            char* pv = (char*)&Vt[cur ^ 1][0] + wave * 1024;
            ASYNC_LD16(gk, pk);
            ASYNC_LD16(gv, pv);
            gk += 8192; gv += 128;
        }

        // K fragments (A-operand) for this wave's key-half:
        // key = kh*32 + kg*16 + c, logical chunk ch*4+quad (row&7 = c&7)
        f16x8 kf[2][2];
        #pragma unroll
        for (int kg = 0; kg < 2; ++kg)
            #pragma unroll
            for (int ch = 0; ch < 2; ++ch)
                kf[kg][ch] = *(const f16x8*)
                    &Kt[cur][(kh*32 + kg*16 + c) * 64 + (((ch*4 + quad) ^ (c & 7)) * 8)];

        // S^T = K Q^T : lane: key = kh*32 + kg*16 + quad*4 + r, qrow = t*16+c
        f32x4 s[2][2];
        #pragma unroll
        for (int t = 0; t < 2; ++t)
            #pragma unroll
            for (int kg = 0; kg < 2; ++kg) {
                s[t][kg] = __builtin_amdgcn_mfma_f32_16x16x32_f16(kf[kg][0], qf[t][0], zero4,   0, 0, 0);
                s[t][kg] = __builtin_amdgcn_mfma_f32_16x16x32_f16(kf[kg][1], qf[t][1], s[t][kg], 0, 0, 0);
            }

        // p = 2^(s') packed into the K=32 A-fragment order: pf8[t] element j
        // holds key (rel. to kh*32) = (j>=4)*16 + quad*4 + (j&3)
        f16x8 pf8[2];
        #pragma unroll
        for (int t = 0; t < 2; ++t) {
            hf4 h4[2];
            #pragma unroll
            for (int u = 0; u < 2; ++u) {
                float p0 = __builtin_amdgcn_exp2f(s[t][u][0]);
                float p1 = __builtin_amdgcn_exp2f(s[t][u][1]);
                float p2 = __builtin_amdgcn_exp2f(s[t][u][2]);
                float p3 = __builtin_amdgcn_exp2f(s[t][u][3]);
                hf2 lo = __builtin_amdgcn_cvt_pkrtz(p0, p1);
                hf2 hi = __builtin_amdgcn_cvt_pkrtz(p2, p3);
                h4[u] = __builtin_shufflevector(lo, hi, 0, 1, 2, 3);
            }
            hf8 h8 = __builtin_shufflevector(h4[0], h4[1], 0, 1, 2, 3, 4, 5, 6, 7);
            pf8[t] = __builtin_bit_cast(f16x8, h8);
        }

        // l += P @ ones  (K=32; with B = ones any k-permutation is valid)
        #pragma unroll
        for (int t = 0; t < 2; ++t)
            lacc[t] = __builtin_amdgcn_mfma_f32_16x16x32_f16(pf8[t], ones8, lacc[t], 0, 0, 0);

        // O += P V  (K=32: B element j = V[kh*32 + key(quad,j)][d=dg*16+c])
        #pragma unroll
        for (int dg = 0; dg < 4; ++dg) {
            f16x4 vf[2];
            #pragma unroll
            for (int u = 0; u < 2; ++u)
                vf[u] = *(const f16x4*)
                    &Vt[cur][(dg*16 + c) * 64 +
                             (((kh*4 + 2*u + (quad >> 1)) ^ (c & 7)) * 8) + (quad & 1) * 4];
            f16x8 v8 = __builtin_shufflevector(vf[0], vf[1], 0, 1, 2, 3, 4, 5, 6, 7);
            #pragma unroll
            for (int t = 0; t < 2; ++t)
                oacc[t][dg] = __builtin_amdgcn_mfma_f32_16x16x32_f16(pf8[t], v8, oacc[t][dg], 0, 0, 0);
        }
        __syncthreads();
    };

    for (int it = 0; it < SLEN / 64 - 2; it += 2) {
        tile(0, true);
        tile(1, true);
    }
    tile(0, true);
    tile(1, false);   // no prefetch: LDS is reused by the merge below

    // --- merge key-half partials (O, l) through LDS, two rounds over t.
    // Round size: 4 qg x 64 lanes x 20 f32 = 20 KB (fits in the 32 KB pool).
    float* mb = (float*)&Kt[0][0];
    #pragma unroll
    for (int t = 0; t < 2; ++t) {
        if (kh == 1) {
            float* p = mb + ((qg * 64 + lane) * 20);
            *(f32x4*)(p +  0) = oacc[t][0];
            *(f32x4*)(p +  4) = oacc[t][1];
            *(f32x4*)(p +  8) = oacc[t][2];
            *(f32x4*)(p + 12) = oacc[t][3];
            *(f32x4*)(p + 16) = lacc[t];
        }
        __syncthreads();
        if (kh == 0) {
            const float* p = mb + ((qg * 64 + lane) * 20);
            f32x4 po[4], pl;
            po[0] = *(const f32x4*)(p +  0);
            po[1] = *(const f32x4*)(p +  4);
            po[2] = *(const f32x4*)(p +  8);
            po[3] = *(const f32x4*)(p + 12);
            pl    = *(const f32x4*)(p + 16);
            #pragma unroll
            for (int r = 0; r < 4; ++r) {
                float linv = 1.0f / (lacc[t][r] + pl[r]);
                int row = qbase + t*16 + quad*4 + r;
                #pragma unroll
                for (int dg = 0; dg < 4; ++dg)
                    ow[((size_t)b * SLEN + row) * EMB + h * DM + dg*16 + c] =
                        (_Float16)((oacc[t][dg][r] + po[dg][r]) * linv);
            }
        }
        __syncthreads();
    }
}

// ---------------------------------------------------------------------------
extern "C" void kernel_launch(void* const* d_in, const int* in_sizes, int n_in,
                              void* d_out, int out_size, void* d_ws, size_t ws_size,
                              hipStream_t stream)
{
    const float* Q  = (const float*)d_in[0];
    const float* K  = (const float*)d_in[1];
    const float* V  = (const float*)d_in[2];
    const float* Wq = (const float*)d_in[3];
    const float* bq = (const float*)d_in[4];
    const float* Wk = (const float*)d_in[5];
    const float* bk = (const float*)d_in[6];
    const float* Wv = (const float*)d_in[7];
    const float* bv = (const float*)d_in[8];
    const float* Wo = (const float*)d_in[9];
    const float* bo = (const float*)d_in[10];
    float* out = (float*)d_out;

    const size_t MN = (size_t)BS * SLEN * NH * DM;   // 4M halves
    const size_t WW = (size_t)EMB * NH * DM;         // 1M halves

    _Float16* base = (_Float16*)d_ws;
    _Float16* Qh   = base;
    _Float16* Kh   = Qh  + MN;
    _Float16* Vh   = Kh  + MN;
    _Float16* WqT  = Vh  + MN;
    _Float16* WkT  = WqT + WW;
    _Float16* WvT  = WkT + WW;
    _Float16* WoT  = WvT + WW;
    _Float16* q_ws = WoT + WW;
    _Float16* k_ws = q_ws + MN;
    _Float16* v_ws = k_ws + MN;
    _Float16* o_ws = v_ws + MN;

    dim3 blk(256);

    prep<<<dim3(2048, 1, 7), blk, 0, stream>>>(Q, K, V, Wq, Wk, Wv, Wo,
                                               Qh, Kh, Vh, WqT, WkT, WvT, WoT);

    gemm_qkv<<<dim3(8, 32, 3), blk, 0, stream>>>(Qh, Kh, Vh, WqT, WkT, WvT,
                                                 bq, bk, bv, q_ws, k_ws, v_ws);

    attn_mfma<<<dim3(SLEN / 128, BS * NH), dim3(512), 0, stream>>>(q_ws, k_ws, v_ws, o_ws);

    gemm_out<<<dim3(8, 32, 1), blk, 0, stream>>>(o_ws, WoT, bo, out);
}